// Round 18
// baseline (654.777 us; speedup 1.0000x reference)
//
#include <hip/hip_runtime.h>
#include <hip/hip_bf16.h>
#include <hip/hip_cooperative_groups.h>
#include <math.h>

namespace cg = cooperative_groups;

#define N_NODES 50000
#define N_EDGES 600000
#define N_GRAPHS 1024
#define H 128
#define VOCAB 32
#define BN_EPS 1e-5f
#define SCAN_BLOCKS ((N_NODES + 255) / 256)   // 196
#define H1_NODES 64
#define H1_BLOCKS ((N_NODES + H1_NODES - 1) / H1_NODES)   // 782
#define EB ((N_EDGES + 255) / 256)            // 2344
#define GM_NODES 16
#define SROW 136
#define ZERO_BYTES ((size_t)N_NODES * 4 + (size_t)N_NODES * VOCAB * 4)
#define ZERO_N16 ((int)(ZERO_BYTES / 16))

typedef short bf8_t __attribute__((ext_vector_type(8)));
typedef float f4_t __attribute__((ext_vector_type(4)));

// ---------------- pass 0: zero cntO + wc32 ----------------
__global__ void k_zero(uint4* __restrict__ p, int n16) {
    int i = blockIdx.x * blockDim.x + threadIdx.x;
    if (i < n16) p[i] = uint4{0u, 0u, 0u, 0u};
}

// ---------------- pass 1: out-degree count + weight prep (fused) ----------------
__global__ void k_count_prep(const int* __restrict__ src, int* __restrict__ cntO,
                             const float* __restrict__ emb, const float* __restrict__ W1,
                             float* __restrict__ emb1,
                             const float* __restrict__ W2, __hip_bfloat16* __restrict__ w2t) {
    int b = blockIdx.x;
    int t = threadIdx.x;
    if (b < EB) {
        int i = b * 256 + t;
        if (i < N_EDGES) atomicAdd(&cntO[src[i]], 1);
    } else if (b < EB + 32) {
        if (t < 128) {
            int v = b - EB;
            float acc = 0.f;
            for (int k = 0; k < H; ++k) acc += emb[v * H + k] * W1[k * H + t];
            emb1[v * H + t] = acc;
        }
    } else {
        if (t < 128) {
            int k = b - EB - 32;
            w2t[(size_t)t * H + k] = __float2bfloat16(W2[(size_t)k * H + t]);
        }
    }
}

// ---------------- pass 2: fused weighted histogram + in-degree (u32 atomics) ----------
__global__ void k_hist32(const int* __restrict__ src, const int* __restrict__ dst,
                         const int* __restrict__ feat, const int* __restrict__ cntO,
                         unsigned* __restrict__ wc,
                         unsigned char* __restrict__ rank8, int E) {
    int i = blockIdx.x * blockDim.x + threadIdx.x;
    if (i >= E) return;
    int s = src[i], d = dst[i], v = feat[s];
    float o = rsqrtf(fmaxf((float)cntO[s], 1.f));
    unsigned q = __float2uint_rn(o * 1048576.0f);   // 2^20 fixpoint
    unsigned old = atomicAdd(&wc[(size_t)d * VOCAB + v], (1u << 27) | q);
    rank8[i] = (unsigned char)(old >> 27);
}

// ---------------- pass 3: per-node bin scan + cntI + per-256-node block sums ----------------
__global__ void k_nodebins(const unsigned* __restrict__ wc,
                           int* __restrict__ cntI, unsigned char* __restrict__ binbase,
                           int* __restrict__ bsum, int n) {
    __shared__ int scnt[256];
    int t = threadIdx.x;
    int wave = t >> 6, lane = t & 63;
    int sub = lane >> 5;
    int l32 = lane & 31;
    int nodeBase = blockIdx.x * 256;
#pragma unroll 4
    for (int it = 0; it < 32; ++it) {
        int local = wave * 64 + it * 2 + sub;
        int node = nodeBase + local;
        int c = 0;
        if (node < n && l32 < VOCAB)
            c = (int)(wc[(size_t)node * VOCAB + l32] >> 27);
        int inc = c;
#pragma unroll
        for (int off = 1; off < VOCAB; off <<= 1) {
            int u = __shfl_up(inc, off, 32);
            if (l32 >= off) inc += u;
        }
        if (node < n && l32 < VOCAB)
            binbase[(size_t)node * VOCAB + l32] = (unsigned char)(inc - c);
        if (l32 == VOCAB - 1) scnt[local] = (node < n) ? inc : 0;
    }
    __syncthreads();
    int node = nodeBase + t;
    if (node < n) cntI[node] = scnt[t];
    __shared__ int red[256];
    red[t] = scnt[t];
    __syncthreads();
    for (int off = 128; off > 0; off >>= 1) {
        if (t < off) red[t] += red[t + off];
        __syncthreads();
    }
    if (t == 0) bsum[blockIdx.x] = red[0];
}

// ---------------- pass 4: scatter-scan with inline (redundant) bsum scan ----------------
__global__ void k_scatterscan(const int* __restrict__ cntI, const int* __restrict__ bsum,
                              int* __restrict__ row_ptr, float* __restrict__ ii,
                              int n, int nb) {
    __shared__ int sb[256];
    __shared__ int sh[256];
    int t = threadIdx.x;
    int bv = (t < nb) ? bsum[t] : 0;
    sb[t] = bv;
    __syncthreads();
    for (int off = 1; off < 256; off <<= 1) {
        int u = (t >= off) ? sb[t - off] : 0;
        __syncthreads();
        sb[t] += u;
        __syncthreads();
    }
    int blockoff = (blockIdx.x == 0) ? 0 : sb[blockIdx.x - 1];
    int i = blockIdx.x * 256 + t;
    int v = (i < n) ? cntI[i] : 0;
    sh[t] = v;
    __syncthreads();
    for (int off = 1; off < 256; off <<= 1) {
        int u = (t >= off) ? sh[t - off] : 0;
        __syncthreads();
        sh[t] += u;
        __syncthreads();
    }
    if (i < n) {
        row_ptr[i] = blockoff + sh[t] - v;
        ii[i] = rsqrtf(fmaxf((float)v, 1.f));
    }
    if (blockIdx.x == 0 && t == 0) row_ptr[n] = sb[nb - 1];
}

// ---------------- pass 5 (fused): atomic-free CSR fill + layer-1 h1 compute ----------------
__global__ void k_fill_h1(const int* __restrict__ src, const int* __restrict__ dst,
                          const int* __restrict__ feat, const int* __restrict__ row_ptr,
                          const unsigned char* __restrict__ binbase,
                          const unsigned char* __restrict__ rank8,
                          int* __restrict__ col,
                          const unsigned* __restrict__ wc,
                          const float* __restrict__ emb1,
                          const float* __restrict__ ii, const int* __restrict__ cntO,
                          const float* __restrict__ b1, __hip_bfloat16* __restrict__ h1) {
    __shared__ float wl[H1_NODES * VOCAB];
    __shared__ float sii[H1_NODES], soi[H1_NODES];
    int tid = threadIdx.x;
    if (blockIdx.x < EB) {
        int i = blockIdx.x * 256 + tid;
        if (i < N_EDGES) {
            int s = src[i], d = dst[i], v = feat[s];
            int slot = row_ptr[d] + (int)binbase[(size_t)d * VOCAB + v] + (int)rank8[i];
            col[slot] = s;
        }
        return;
    }
    int hb = blockIdx.x - EB;
    int j = tid & 127;
    int g = tid >> 7;
    float ev[VOCAB];
#pragma unroll
    for (int v = 0; v < VOCAB; ++v) ev[v] = emb1[v * H + j];
    float bj = b1[j];

    int node0 = hb * H1_NODES;
    int nn = min(H1_NODES, N_NODES - node0);
    const unsigned* wsrc = wc + (size_t)node0 * VOCAB;
    for (int i = tid; i < nn * VOCAB; i += 256) {
        unsigned p = wsrc[i];
        wl[i] = (float)(p & 0x07FFFFFFu) * (1.0f / 1048576.0f);
    }
    for (int i = tid; i < nn; i += 256) {
        sii[i] = ii[node0 + i];
        soi[i] = rsqrtf(fmaxf((float)cntO[node0 + i], 1.f));
    }
    __syncthreads();

    int rbeg = g * 32;
    int rend = min(rbeg + 32, nn);
    for (int r = rbeg; r < rend; ++r) {
        const float4* wr = (const float4*)(wl + r * VOCAB);
        float acc = 0.f;
#pragma unroll
        for (int q = 0; q < VOCAB / 4; ++q) {
            float4 w4 = wr[q];
            acc += w4.x * ev[4 * q] + w4.y * ev[4 * q + 1]
                 + w4.z * ev[4 * q + 2] + w4.w * ev[4 * q + 3];
        }
        float val = fmaxf(acc * sii[r] + bj, 0.f);
        h1[(size_t)(node0 + r) * H + j] = __float2bfloat16(val * soi[r]);
    }
}

// ---------------- layer 2 (fused): gather into LDS -> MFMA, 16-node tile ----------------
__global__ __launch_bounds__(256) void k_gather_mfma(
        const __hip_bfloat16* __restrict__ h,
        const int* __restrict__ row_ptr, const int* __restrict__ col,
        const __hip_bfloat16* __restrict__ WT,
        const float* __restrict__ ii, const float* __restrict__ b,
        __hip_bfloat16* __restrict__ outp, int n) {
    __shared__ __hip_bfloat16 sA[GM_NODES * SROW];
    int tid = threadIdx.x;
    int wave = tid >> 6;
    int lane = tid & 63;
    int l16 = lane & 15;
    int sub = lane >> 4;
    int co = l16 * 8;
    int base = blockIdx.x * GM_NODES;

    int local = wave * 4 + sub;
    int node = base + local;
    float a0 = 0.f, a1 = 0.f, a2 = 0.f, a3 = 0.f;
    float a4 = 0.f, a5 = 0.f, a6 = 0.f, a7 = 0.f;
    if (node < n) {
        int beg = row_ptr[node];
        int end = row_ptr[node + 1];
        int e = beg;
        for (; e + 16 <= end; e += 16) {
            int s[16];
            uint4 v[16];
#pragma unroll
            for (int k = 0; k < 16; ++k) s[k] = col[e + k];
#pragma unroll
            for (int k = 0; k < 16; ++k)
                v[k] = *(const uint4*)(h + (size_t)s[k] * H + co);
#pragma unroll
            for (int k = 0; k < 16; ++k) {
                float2 f0 = __bfloat1622float2(*(__hip_bfloat162*)&v[k].x);
                float2 f1 = __bfloat1622float2(*(__hip_bfloat162*)&v[k].y);
                float2 f2 = __bfloat1622float2(*(__hip_bfloat162*)&v[k].z);
                float2 f3 = __bfloat1622float2(*(__hip_bfloat162*)&v[k].w);
                a0 += f0.x; a1 += f0.y; a2 += f1.x; a3 += f1.y;
                a4 += f2.x; a5 += f2.y; a6 += f3.x; a7 += f3.y;
            }
        }
        if (e < end) {
            int s[16];
            uint4 v[16];
#pragma unroll
            for (int k = 0; k < 16; ++k) s[k] = col[(e + k < end) ? e + k : e];
#pragma unroll
            for (int k = 0; k < 16; ++k)
                v[k] = *(const uint4*)(h + (size_t)s[k] * H + co);
#pragma unroll
            for (int k = 0; k < 16; ++k) {
                float mk = (e + k < end) ? 1.f : 0.f;
                float2 f0 = __bfloat1622float2(*(__hip_bfloat162*)&v[k].x);
                float2 f1 = __bfloat1622float2(*(__hip_bfloat162*)&v[k].y);
                float2 f2 = __bfloat1622float2(*(__hip_bfloat162*)&v[k].z);
                float2 f3 = __bfloat1622float2(*(__hip_bfloat162*)&v[k].w);
                a0 += mk * f0.x; a1 += mk * f0.y; a2 += mk * f1.x; a3 += mk * f1.y;
                a4 += mk * f2.x; a5 += mk * f2.y; a6 += mk * f3.x; a7 += mk * f3.y;
            }
        }
    }
    __hip_bfloat162 o0 = __float22bfloat162_rn(make_float2(a0, a1));
    __hip_bfloat162 o1 = __float22bfloat162_rn(make_float2(a2, a3));
    __hip_bfloat162 o2 = __float22bfloat162_rn(make_float2(a4, a5));
    __hip_bfloat162 o3 = __float22bfloat162_rn(make_float2(a6, a7));
    uint4 ov;
    ov.x = *(unsigned*)&o0; ov.y = *(unsigned*)&o1;
    ov.z = *(unsigned*)&o2; ov.w = *(unsigned*)&o3;
    *(uint4*)(&sA[local * SROW + co]) = ov;
    __syncthreads();

    int rl = l16;
    int kg = sub;
    f4_t acc[2];
    acc[0] = f4_t{0.f, 0.f, 0.f, 0.f};
    acc[1] = f4_t{0.f, 0.f, 0.f, 0.f};
    const __hip_bfloat16* arow = &sA[rl * SROW + kg * 8];
#pragma unroll
    for (int ks = 0; ks < 4; ++ks) {
        bf8_t a = *(const bf8_t*)(arow + ks * 32);
#pragma unroll
        for (int t = 0; t < 2; ++t) {
            int ct = wave * 2 + t;
            bf8_t bf = *(const bf8_t*)(WT + (size_t)(ct * 16 + rl) * H + ks * 32 + kg * 8);
            acc[t] = __builtin_amdgcn_mfma_f32_16x16x32_bf16(a, bf, acc[t], 0, 0, 0);
        }
    }
    int rbase = base + kg * 4;
#pragma unroll
    for (int r = 0; r < 4; ++r) {
        int nd = rbase + r;
        if (nd < n) {
            float s = ii[nd];
#pragma unroll
            for (int t = 0; t < 2; ++t) {
                int c = (wave * 2 + t) * 16 + rl;
                float v = acc[t][r] * s + b[c];
                outp[(size_t)nd * H + c] = __float2bfloat16(fmaxf(v, 0.f));
            }
        }
    }
}

// ---------------- head: single cooperative kernel (pool->mlp1->bn0->mlp2->bn1->head) ----------------
__global__ void k_headall(const __hip_bfloat16* __restrict__ h, const int* __restrict__ gid,
                          const float* __restrict__ e1w, const float* __restrict__ e1b,
                          const float* __restrict__ bn0g, const float* __restrict__ bn0b,
                          const float* __restrict__ e2w, const float* __restrict__ e2b,
                          const float* __restrict__ bn1g, const float* __restrict__ bn1b,
                          const float* __restrict__ e3w, const float* __restrict__ e3b,
                          const float* __restrict__ e4w, const float* __restrict__ e4b,
                          const float* __restrict__ e5w, const float* __restrict__ e5b,
                          float* __restrict__ t1, float* __restrict__ t2,
                          float* __restrict__ stats, float* __restrict__ out, int n) {
    cg::grid_group grid = cg::this_grid();
    __shared__ int bnd[2];
    __shared__ float row[128];
    __shared__ float x[128];
    __shared__ float rs[128], rs2[128];
    __shared__ float h3[64], h4[32];
    int g = blockIdx.x, t = threadIdx.x;

    // phase 1: pool + mlp1 -> t1
    if (t == 0) {
        int lo = 0, hi = n;
        while (lo < hi) { int m = (lo + hi) >> 1; if (gid[m] < g) lo = m + 1; else hi = m; }
        bnd[0] = lo;
        int lo2 = lo, hi2 = n;
        while (lo2 < hi2) { int m = (lo2 + hi2) >> 1; if (gid[m] < g + 1) lo2 = m + 1; else hi2 = m; }
        bnd[1] = lo2;
    }
    __syncthreads();
    int beg = bnd[0], end = bnd[1];
    float s = 0.f;
    for (int i = beg; i < end; ++i) s += __bfloat162float(h[(size_t)i * H + t]);
    row[t] = s / fmaxf((float)(end - beg), 1.f);
    __syncthreads();
    {
        float acc = e1b[t];
        for (int k = 0; k < H; ++k) acc += row[k] * e1w[k * H + t];
        t1[g * H + t] = acc;
    }
    grid.sync();

    // phase 2: bnstat(t1) -> stats[0..255], blocks 0..127 (block c = column c)
    if (g < H) {
        float ss = 0.f, ss2 = 0.f;
        for (int r = t; r < N_GRAPHS; r += 128) {
            float v = t1[r * H + g];
            ss += v; ss2 += v * v;
        }
        rs[t] = ss; rs2[t] = ss2;
        __syncthreads();
        for (int off = 64; off > 0; off >>= 1) {
            if (t < off) { rs[t] += rs[t + off]; rs2[t] += rs2[t + off]; }
            __syncthreads();
        }
        if (t == 0) {
            float mu = rs[0] / N_GRAPHS;
            stats[g] = mu;
            stats[H + g] = rs2[0] / N_GRAPHS - mu * mu;
        }
    }
    grid.sync();

    // phase 3: bn0 + lrelu + mlp2 -> t2
    {
        float v = t1[g * H + t];
        v = (v - stats[t]) * rsqrtf(stats[H + t] + BN_EPS) * bn0g[t] + bn0b[t];
        x[t] = (v >= 0.f) ? v : 0.05f * v;
    }
    __syncthreads();
    {
        float acc = e2b[t];
        for (int k = 0; k < H; ++k) acc += x[k] * e2w[k * H + t];
        t2[g * H + t] = acc;
    }
    grid.sync();

    // phase 4: bnstat(t2) -> stats[256..511]
    if (g < H) {
        float ss = 0.f, ss2 = 0.f;
        for (int r = t; r < N_GRAPHS; r += 128) {
            float v = t2[r * H + g];
            ss += v; ss2 += v * v;
        }
        rs[t] = ss; rs2[t] = ss2;
        __syncthreads();
        for (int off = 64; off > 0; off >>= 1) {
            if (t < off) { rs[t] += rs[t + off]; rs2[t] += rs2[t + off]; }
            __syncthreads();
        }
        if (t == 0) {
            float mu = rs[0] / N_GRAPHS;
            stats[2 * H + g] = mu;
            stats[3 * H + g] = rs2[0] / N_GRAPHS - mu * mu;
        }
    }
    grid.sync();

    // phase 5: bn1 + lrelu -> e3 -> e4 -> e5 -> log_softmax
    {
        float v = t2[g * H + t];
        v = (v - stats[2 * H + t]) * rsqrtf(stats[3 * H + t] + BN_EPS) * bn1g[t] + bn1b[t];
        x[t] = (v >= 0.f) ? v : 0.05f * v;
    }
    __syncthreads();
    if (t < 64) {
        float a = e3b[t];
        for (int k = 0; k < 128; ++k) a += x[k] * e3w[k * 64 + t];
        h3[t] = (a >= 0.f) ? a : 0.1f * a;
    }
    __syncthreads();
    if (t < 32) {
        float a = e4b[t];
        for (int k = 0; k < 64; ++k) a += h3[k] * e4w[k * 32 + t];
        h4[t] = (a >= 0.f) ? a : 0.1f * a;
    }
    __syncthreads();
    if (t == 0) {
        float y0 = e5b[0], y1 = e5b[1];
        for (int k = 0; k < 32; ++k) {
            y0 += h4[k] * e5w[2 * k];
            y1 += h4[k] * e5w[2 * k + 1];
        }
        float m = fmaxf(y0, y1);
        float l = m + logf(expf(y0 - m) + expf(y1 - m));
        out[2 * g] = y0 - l;
        out[2 * g + 1] = y1 - l;
    }
}

extern "C" void kernel_launch(void* const* d_in, const int* in_sizes, int n_in,
                              void* d_out, int out_size, void* d_ws, size_t ws_size,
                              hipStream_t stream) {
    const int*   node_feat = (const int*)d_in[0];
    const int*   edge_src  = (const int*)d_in[1];
    const int*   edge_dst  = (const int*)d_in[2];
    const int*   graph_ids = (const int*)d_in[3];
    const float* emb  = (const float*)d_in[4];
    const float* W1   = (const float*)d_in[5];
    const float* b1   = (const float*)d_in[6];
    const float* W2   = (const float*)d_in[7];
    const float* b2   = (const float*)d_in[8];
    const float* e1_w = (const float*)d_in[9];
    const float* e1_b = (const float*)d_in[10];
    const float* e2_w = (const float*)d_in[11];
    const float* e2_b = (const float*)d_in[12];
    const float* e3_w = (const float*)d_in[13];
    const float* e3_b = (const float*)d_in[14];
    const float* e4_w = (const float*)d_in[15];
    const float* e4_b = (const float*)d_in[16];
    const float* e5_w = (const float*)d_in[17];
    const float* e5_b = (const float*)d_in[18];
    const float* bn0_g = (const float*)d_in[19];
    const float* bn0_b = (const float*)d_in[20];
    const float* bn1_g = (const float*)d_in[21];
    const float* bn1_b = (const float*)d_in[22];
    float* out = (float*)d_out;

    // workspace layout
    float* ws = (float*)d_ws;
    float* bufA = ws;
    __hip_bfloat16* h2bf = (__hip_bfloat16*)bufA;                         // N*H bf16 (h2)
    __hip_bfloat16* h1bf = (__hip_bfloat16*)(bufA + (size_t)N_NODES * H); // N*H bf16
    int*   cntO = (int*)(h1bf + (size_t)N_NODES * H);                     // 50000
    unsigned* wc = (unsigned*)(cntO + N_NODES);                           // N*32 u32 (6.4MB)
    float* ii   = (float*)(wc + (size_t)N_NODES * VOCAB);
    int*   cntI = (int*)(ii + N_NODES);
    int*   row_ptr = cntI + N_NODES;                                      // 50001 -> pad 50048
    int*   col  = row_ptr + 50048;                                        // 600000
    unsigned char* binbase = (unsigned char*)(col + N_EDGES);             // N*32
    unsigned char* rank8   = binbase + (size_t)N_NODES * VOCAB;           // 600000
    float* t1   = (float*)(rank8 + ((N_EDGES + 63) & ~63));
    float* t2   = t1 + N_GRAPHS * H;
    float* stats = t2 + N_GRAPHS * H;                                     // 512
    int*   bsum  = (int*)(stats + 4 * H);                                 // 256
    float* emb1  = (float*)(bsum + 256);                                  // 4096
    __hip_bfloat16* w2t = (__hip_bfloat16*)(emb1 + VOCAB * H);            // 16384 bf16

    // zero cntO + wc
    k_zero<<<(ZERO_N16 + 255) / 256, 256, 0, stream>>>((uint4*)cntO, ZERO_N16);

    k_count_prep<<<EB + 160, 256, 0, stream>>>(edge_src, cntO, emb, W1, emb1, W2, w2t);
    k_hist32<<<EB, 256, 0, stream>>>(edge_src, edge_dst, node_feat, cntO, wc, rank8, N_EDGES);
    k_nodebins<<<SCAN_BLOCKS, 256, 0, stream>>>(wc, cntI, binbase, bsum, N_NODES);
    k_scatterscan<<<SCAN_BLOCKS, 256, 0, stream>>>(cntI, bsum, row_ptr, ii, N_NODES, SCAN_BLOCKS);
    k_fill_h1<<<EB + H1_BLOCKS, 256, 0, stream>>>(edge_src, edge_dst, node_feat, row_ptr,
                                                  binbase, rank8, col,
                                                  wc, emb1, ii, cntO, b1, h1bf);

    // layer 2: fused gather->LDS->MFMA
    k_gather_mfma<<<(N_NODES + GM_NODES - 1) / GM_NODES, 256, 0, stream>>>(
        h1bf, row_ptr, col, w2t, ii, b2, h2bf, N_NODES);

    // head: single cooperative kernel (grid-wide syncs replace 4 kernel boundaries)
    int nNodes = N_NODES;
    void* args[] = {(void*)&h2bf, (void*)&graph_ids,
                    (void*)&e1_w, (void*)&e1_b, (void*)&bn0_g, (void*)&bn0_b,
                    (void*)&e2_w, (void*)&e2_b, (void*)&bn1_g, (void*)&bn1_b,
                    (void*)&e3_w, (void*)&e3_b, (void*)&e4_w, (void*)&e4_b,
                    (void*)&e5_w, (void*)&e5_b,
                    (void*)&t1, (void*)&t2, (void*)&stats, (void*)&out, (void*)&nNodes};
    hipLaunchCooperativeKernel((void*)k_headall, dim3(N_GRAPHS), dim3(128), args, 0, stream);
}

// Round 19
// 234.557 us; speedup vs baseline: 2.7915x; 2.7915x over previous
//
#include <hip/hip_runtime.h>
#include <hip/hip_bf16.h>
#include <math.h>

#define N_NODES 50000
#define N_EDGES 600000
#define N_GRAPHS 1024
#define H 128
#define VOCAB 32
#define BN_EPS 1e-5f
#define SCAN_BLOCKS ((N_NODES + 255) / 256)   // 196
#define H1_NODES 64
#define H1_BLOCKS ((N_NODES + H1_NODES - 1) / H1_NODES)   // 782
#define EB ((N_EDGES + 255) / 256)            // 2344
#define GM_NODES 16
#define SROW 136
#define FIXP 1073741824.0f   // 2^30
// cntO (50000 int) + wc32 (N*32 u32) + statq (512 i64) contiguous
#define ZERO_BYTES ((size_t)N_NODES * 4 + (size_t)N_NODES * VOCAB * 4 + 512 * 8)
#define ZERO_N16 ((int)(ZERO_BYTES / 16))

typedef short bf8_t __attribute__((ext_vector_type(8)));
typedef float f4_t __attribute__((ext_vector_type(4)));

// ---------------- pass 0: zero cntO + wc32 + statq ----------------
__global__ void k_zero(uint4* __restrict__ p, int n16) {
    int i = blockIdx.x * blockDim.x + threadIdx.x;
    if (i < n16) p[i] = uint4{0u, 0u, 0u, 0u};
}

// ---------------- pass 1: out-degree count + weight prep (fused) ----------------
__global__ void k_count_prep(const int* __restrict__ src, int* __restrict__ cntO,
                             const float* __restrict__ emb, const float* __restrict__ W1,
                             float* __restrict__ emb1,
                             const float* __restrict__ W2, __hip_bfloat16* __restrict__ w2t) {
    int b = blockIdx.x;
    int t = threadIdx.x;
    if (b < EB) {
        int i = b * 256 + t;
        if (i < N_EDGES) atomicAdd(&cntO[src[i]], 1);
    } else if (b < EB + 32) {
        if (t < 128) {
            int v = b - EB;
            float acc = 0.f;
            for (int k = 0; k < H; ++k) acc += emb[v * H + k] * W1[k * H + t];
            emb1[v * H + t] = acc;
        }
    } else {
        if (t < 128) {
            int k = b - EB - 32;
            w2t[(size_t)t * H + k] = __float2bfloat16(W2[(size_t)k * H + t]);
        }
    }
}

// ---------------- pass 2: fused weighted histogram + in-degree (u32 atomics) ----------
__global__ void k_hist32(const int* __restrict__ src, const int* __restrict__ dst,
                         const int* __restrict__ feat, const int* __restrict__ cntO,
                         unsigned* __restrict__ wc,
                         unsigned char* __restrict__ rank8, int E) {
    int i = blockIdx.x * blockDim.x + threadIdx.x;
    if (i >= E) return;
    int s = src[i], d = dst[i], v = feat[s];
    float o = rsqrtf(fmaxf((float)cntO[s], 1.f));
    unsigned q = __float2uint_rn(o * 1048576.0f);   // 2^20 fixpoint
    unsigned old = atomicAdd(&wc[(size_t)d * VOCAB + v], (1u << 27) | q);
    rank8[i] = (unsigned char)(old >> 27);
}

// ---------------- pass 3: per-node bin scan + cntI + per-256-node block sums ----------------
__global__ void k_nodebins(const unsigned* __restrict__ wc,
                           int* __restrict__ cntI, unsigned char* __restrict__ binbase,
                           int* __restrict__ bsum, int n) {
    __shared__ int scnt[256];
    int t = threadIdx.x;
    int wave = t >> 6, lane = t & 63;
    int sub = lane >> 5;
    int l32 = lane & 31;
    int nodeBase = blockIdx.x * 256;
#pragma unroll 4
    for (int it = 0; it < 32; ++it) {
        int local = wave * 64 + it * 2 + sub;
        int node = nodeBase + local;
        int c = 0;
        if (node < n && l32 < VOCAB)
            c = (int)(wc[(size_t)node * VOCAB + l32] >> 27);
        int inc = c;
#pragma unroll
        for (int off = 1; off < VOCAB; off <<= 1) {
            int u = __shfl_up(inc, off, 32);
            if (l32 >= off) inc += u;
        }
        if (node < n && l32 < VOCAB)
            binbase[(size_t)node * VOCAB + l32] = (unsigned char)(inc - c);
        if (l32 == VOCAB - 1) scnt[local] = (node < n) ? inc : 0;
    }
    __syncthreads();
    int node = nodeBase + t;
    if (node < n) cntI[node] = scnt[t];
    __shared__ int red[256];
    red[t] = scnt[t];
    __syncthreads();
    for (int off = 128; off > 0; off >>= 1) {
        if (t < off) red[t] += red[t + off];
        __syncthreads();
    }
    if (t == 0) bsum[blockIdx.x] = red[0];
}

// ---------------- pass 4: scatter-scan with inline (redundant) bsum scan ----------------
__global__ void k_scatterscan(const int* __restrict__ cntI, const int* __restrict__ bsum,
                              int* __restrict__ row_ptr, float* __restrict__ ii,
                              int n, int nb) {
    __shared__ int sb[256];
    __shared__ int sh[256];
    int t = threadIdx.x;
    int bv = (t < nb) ? bsum[t] : 0;
    sb[t] = bv;
    __syncthreads();
    for (int off = 1; off < 256; off <<= 1) {
        int u = (t >= off) ? sb[t - off] : 0;
        __syncthreads();
        sb[t] += u;
        __syncthreads();
    }
    int blockoff = (blockIdx.x == 0) ? 0 : sb[blockIdx.x - 1];
    int i = blockIdx.x * 256 + t;
    int v = (i < n) ? cntI[i] : 0;
    sh[t] = v;
    __syncthreads();
    for (int off = 1; off < 256; off <<= 1) {
        int u = (t >= off) ? sh[t - off] : 0;
        __syncthreads();
        sh[t] += u;
        __syncthreads();
    }
    if (i < n) {
        row_ptr[i] = blockoff + sh[t] - v;
        ii[i] = rsqrtf(fmaxf((float)v, 1.f));
    }
    if (blockIdx.x == 0 && t == 0) row_ptr[n] = sb[nb - 1];
}

// ---------------- pass 5 (fused): atomic-free CSR fill + layer-1 h1 compute ----------------
__global__ void k_fill_h1(const int* __restrict__ src, const int* __restrict__ dst,
                          const int* __restrict__ feat, const int* __restrict__ row_ptr,
                          const unsigned char* __restrict__ binbase,
                          const unsigned char* __restrict__ rank8,
                          int* __restrict__ col,
                          const unsigned* __restrict__ wc,
                          const float* __restrict__ emb1,
                          const float* __restrict__ ii, const int* __restrict__ cntO,
                          const float* __restrict__ b1, __hip_bfloat16* __restrict__ h1) {
    __shared__ float wl[H1_NODES * VOCAB];
    __shared__ float sii[H1_NODES], soi[H1_NODES];
    int tid = threadIdx.x;
    if (blockIdx.x < EB) {
        int i = blockIdx.x * 256 + tid;
        if (i < N_EDGES) {
            int s = src[i], d = dst[i], v = feat[s];
            int slot = row_ptr[d] + (int)binbase[(size_t)d * VOCAB + v] + (int)rank8[i];
            col[slot] = s;
        }
        return;
    }
    int hb = blockIdx.x - EB;
    int j = tid & 127;
    int g = tid >> 7;
    float ev[VOCAB];
#pragma unroll
    for (int v = 0; v < VOCAB; ++v) ev[v] = emb1[v * H + j];
    float bj = b1[j];

    int node0 = hb * H1_NODES;
    int nn = min(H1_NODES, N_NODES - node0);
    const unsigned* wsrc = wc + (size_t)node0 * VOCAB;
    for (int i = tid; i < nn * VOCAB; i += 256) {
        unsigned p = wsrc[i];
        wl[i] = (float)(p & 0x07FFFFFFu) * (1.0f / 1048576.0f);
    }
    for (int i = tid; i < nn; i += 256) {
        sii[i] = ii[node0 + i];
        soi[i] = rsqrtf(fmaxf((float)cntO[node0 + i], 1.f));
    }
    __syncthreads();

    int rbeg = g * 32;
    int rend = min(rbeg + 32, nn);
    for (int r = rbeg; r < rend; ++r) {
        const float4* wr = (const float4*)(wl + r * VOCAB);
        float acc = 0.f;
#pragma unroll
        for (int q = 0; q < VOCAB / 4; ++q) {
            float4 w4 = wr[q];
            acc += w4.x * ev[4 * q] + w4.y * ev[4 * q + 1]
                 + w4.z * ev[4 * q + 2] + w4.w * ev[4 * q + 3];
        }
        float val = fmaxf(acc * sii[r] + bj, 0.f);
        h1[(size_t)(node0 + r) * H + j] = __float2bfloat16(val * soi[r]);
    }
}

// ---------------- layer 2 (fused): gather into LDS -> MFMA, 16-node tile ----------------
__global__ __launch_bounds__(256) void k_gather_mfma(
        const __hip_bfloat16* __restrict__ h,
        const int* __restrict__ row_ptr, const int* __restrict__ col,
        const __hip_bfloat16* __restrict__ WT,
        const float* __restrict__ ii, const float* __restrict__ b,
        __hip_bfloat16* __restrict__ outp, int n) {
    __shared__ __hip_bfloat16 sA[GM_NODES * SROW];
    int tid = threadIdx.x;
    int wave = tid >> 6;
    int lane = tid & 63;
    int l16 = lane & 15;
    int sub = lane >> 4;
    int co = l16 * 8;
    int base = blockIdx.x * GM_NODES;

    int local = wave * 4 + sub;
    int node = base + local;
    float a0 = 0.f, a1 = 0.f, a2 = 0.f, a3 = 0.f;
    float a4 = 0.f, a5 = 0.f, a6 = 0.f, a7 = 0.f;
    if (node < n) {
        int beg = row_ptr[node];
        int end = row_ptr[node + 1];
        int e = beg;
        for (; e + 16 <= end; e += 16) {
            int s[16];
            uint4 v[16];
#pragma unroll
            for (int k = 0; k < 16; ++k) s[k] = col[e + k];
#pragma unroll
            for (int k = 0; k < 16; ++k)
                v[k] = *(const uint4*)(h + (size_t)s[k] * H + co);
#pragma unroll
            for (int k = 0; k < 16; ++k) {
                float2 f0 = __bfloat1622float2(*(__hip_bfloat162*)&v[k].x);
                float2 f1 = __bfloat1622float2(*(__hip_bfloat162*)&v[k].y);
                float2 f2 = __bfloat1622float2(*(__hip_bfloat162*)&v[k].z);
                float2 f3 = __bfloat1622float2(*(__hip_bfloat162*)&v[k].w);
                a0 += f0.x; a1 += f0.y; a2 += f1.x; a3 += f1.y;
                a4 += f2.x; a5 += f2.y; a6 += f3.x; a7 += f3.y;
            }
        }
        if (e < end) {
            int s[16];
            uint4 v[16];
#pragma unroll
            for (int k = 0; k < 16; ++k) s[k] = col[(e + k < end) ? e + k : e];
#pragma unroll
            for (int k = 0; k < 16; ++k)
                v[k] = *(const uint4*)(h + (size_t)s[k] * H + co);
#pragma unroll
            for (int k = 0; k < 16; ++k) {
                float mk = (e + k < end) ? 1.f : 0.f;
                float2 f0 = __bfloat1622float2(*(__hip_bfloat162*)&v[k].x);
                float2 f1 = __bfloat1622float2(*(__hip_bfloat162*)&v[k].y);
                float2 f2 = __bfloat1622float2(*(__hip_bfloat162*)&v[k].z);
                float2 f3 = __bfloat1622float2(*(__hip_bfloat162*)&v[k].w);
                a0 += mk * f0.x; a1 += mk * f0.y; a2 += mk * f1.x; a3 += mk * f1.y;
                a4 += mk * f2.x; a5 += mk * f2.y; a6 += mk * f3.x; a7 += mk * f3.y;
            }
        }
    }
    __hip_bfloat162 o0 = __float22bfloat162_rn(make_float2(a0, a1));
    __hip_bfloat162 o1 = __float22bfloat162_rn(make_float2(a2, a3));
    __hip_bfloat162 o2 = __float22bfloat162_rn(make_float2(a4, a5));
    __hip_bfloat162 o3 = __float22bfloat162_rn(make_float2(a6, a7));
    uint4 ov;
    ov.x = *(unsigned*)&o0; ov.y = *(unsigned*)&o1;
    ov.z = *(unsigned*)&o2; ov.w = *(unsigned*)&o3;
    *(uint4*)(&sA[local * SROW + co]) = ov;
    __syncthreads();

    int rl = l16;
    int kg = sub;
    f4_t acc[2];
    acc[0] = f4_t{0.f, 0.f, 0.f, 0.f};
    acc[1] = f4_t{0.f, 0.f, 0.f, 0.f};
    const __hip_bfloat16* arow = &sA[rl * SROW + kg * 8];
#pragma unroll
    for (int ks = 0; ks < 4; ++ks) {
        bf8_t a = *(const bf8_t*)(arow + ks * 32);
#pragma unroll
        for (int t = 0; t < 2; ++t) {
            int ct = wave * 2 + t;
            bf8_t bf = *(const bf8_t*)(WT + (size_t)(ct * 16 + rl) * H + ks * 32 + kg * 8);
            acc[t] = __builtin_amdgcn_mfma_f32_16x16x32_bf16(a, bf, acc[t], 0, 0, 0);
        }
    }
    int rbase = base + kg * 4;
#pragma unroll
    for (int r = 0; r < 4; ++r) {
        int nd = rbase + r;
        if (nd < n) {
            float s = ii[nd];
#pragma unroll
            for (int t = 0; t < 2; ++t) {
                int c = (wave * 2 + t) * 16 + rl;
                float v = acc[t][r] * s + b[c];
                outp[(size_t)nd * H + c] = __float2bfloat16(fmaxf(v, 0.f));
            }
        }
    }
}

// ---------------- pooling + mlp1 + BN0-stat accumulation (fixpoint i64 atomics) -------
__global__ void k_poolmlp1(const __hip_bfloat16* __restrict__ h, const int* __restrict__ gid,
                           const float* __restrict__ e1w, const float* __restrict__ e1b,
                           float* __restrict__ t1,
                           unsigned long long* __restrict__ statq, int n) {
    __shared__ int bnd[2];
    __shared__ float row[128];
    int g = blockIdx.x, t = threadIdx.x;
    if (t == 0) {
        int lo = 0, hi = n;
        while (lo < hi) { int m = (lo + hi) >> 1; if (gid[m] < g) lo = m + 1; else hi = m; }
        bnd[0] = lo;
        int lo2 = lo, hi2 = n;
        while (lo2 < hi2) { int m = (lo2 + hi2) >> 1; if (gid[m] < g + 1) lo2 = m + 1; else hi2 = m; }
        bnd[1] = lo2;
    }
    __syncthreads();
    int beg = bnd[0], end = bnd[1];
    float s = 0.f;
    for (int i = beg; i < end; ++i) s += __bfloat162float(h[(size_t)i * H + t]);
    row[t] = s / fmaxf((float)(end - beg), 1.f);
    __syncthreads();
    float acc = e1b[t];
    for (int k = 0; k < H; ++k) acc += row[k] * e1w[k * H + t];
    t1[g * H + t] = acc;
    // deterministic fixpoint stat accumulation
    atomicAdd(&statq[t],     (unsigned long long)(long long)llrintf(acc * FIXP));
    atomicAdd(&statq[H + t], (unsigned long long)(long long)llrintf(acc * acc * FIXP));
}

// ---------------- bn0 + lrelu + mlp2 + BN1-stat accumulation ----------------
__global__ void k_mlp2bn(const float* __restrict__ t1,
                         const unsigned long long* __restrict__ statq,
                         unsigned long long* __restrict__ statq2,
                         const float* __restrict__ gam, const float* __restrict__ bet,
                         const float* __restrict__ W, const float* __restrict__ bias,
                         float* __restrict__ t2) {
    __shared__ float x[128];
    int g = blockIdx.x, t = threadIdx.x;
    float mu  = (float)(long long)statq[t]     * (1.f / FIXP) / N_GRAPHS;
    float ex2 = (float)(long long)statq[H + t] * (1.f / FIXP) / N_GRAPHS;
    float var = ex2 - mu * mu;
    float v = t1[g * H + t];
    v = (v - mu) * rsqrtf(var + BN_EPS) * gam[t] + bet[t];
    x[t] = (v >= 0.f) ? v : 0.05f * v;
    __syncthreads();
    float acc = bias[t];
    for (int k = 0; k < H; ++k) acc += x[k] * W[k * H + t];
    t2[g * H + t] = acc;
    atomicAdd(&statq2[t],     (unsigned long long)(long long)llrintf(acc * FIXP));
    atomicAdd(&statq2[H + t], (unsigned long long)(long long)llrintf(acc * acc * FIXP));
}

// ---------------- bn1 + lrelu -> e3 -> e4 -> e5 -> log_softmax ----------------
__global__ void k_head(const float* __restrict__ t2,
                       const unsigned long long* __restrict__ statq2,
                       const float* __restrict__ gam, const float* __restrict__ bet,
                       const float* __restrict__ e3w, const float* __restrict__ e3b,
                       const float* __restrict__ e4w, const float* __restrict__ e4b,
                       const float* __restrict__ e5w, const float* __restrict__ e5b,
                       float* __restrict__ out) {
    __shared__ float x[128], h3[64], h4[32];
    int g = blockIdx.x, t = threadIdx.x;
    float mu  = (float)(long long)statq2[t]     * (1.f / FIXP) / N_GRAPHS;
    float ex2 = (float)(long long)statq2[H + t] * (1.f / FIXP) / N_GRAPHS;
    float var = ex2 - mu * mu;
    float v = t2[g * H + t];
    v = (v - mu) * rsqrtf(var + BN_EPS) * gam[t] + bet[t];
    x[t] = (v >= 0.f) ? v : 0.05f * v;
    __syncthreads();
    if (t < 64) {
        float a = e3b[t];
        for (int k = 0; k < 128; ++k) a += x[k] * e3w[k * 64 + t];
        h3[t] = (a >= 0.f) ? a : 0.1f * a;
    }
    __syncthreads();
    if (t < 32) {
        float a = e4b[t];
        for (int k = 0; k < 64; ++k) a += h3[k] * e4w[k * 32 + t];
        h4[t] = (a >= 0.f) ? a : 0.1f * a;
    }
    __syncthreads();
    if (t == 0) {
        float y0 = e5b[0], y1 = e5b[1];
        for (int k = 0; k < 32; ++k) {
            y0 += h4[k] * e5w[2 * k];
            y1 += h4[k] * e5w[2 * k + 1];
        }
        float m = fmaxf(y0, y1);
        float l = m + logf(expf(y0 - m) + expf(y1 - m));
        out[2 * g] = y0 - l;
        out[2 * g + 1] = y1 - l;
    }
}

extern "C" void kernel_launch(void* const* d_in, const int* in_sizes, int n_in,
                              void* d_out, int out_size, void* d_ws, size_t ws_size,
                              hipStream_t stream) {
    const int*   node_feat = (const int*)d_in[0];
    const int*   edge_src  = (const int*)d_in[1];
    const int*   edge_dst  = (const int*)d_in[2];
    const int*   graph_ids = (const int*)d_in[3];
    const float* emb  = (const float*)d_in[4];
    const float* W1   = (const float*)d_in[5];
    const float* b1   = (const float*)d_in[6];
    const float* W2   = (const float*)d_in[7];
    const float* b2   = (const float*)d_in[8];
    const float* e1_w = (const float*)d_in[9];
    const float* e1_b = (const float*)d_in[10];
    const float* e2_w = (const float*)d_in[11];
    const float* e2_b = (const float*)d_in[12];
    const float* e3_w = (const float*)d_in[13];
    const float* e3_b = (const float*)d_in[14];
    const float* e4_w = (const float*)d_in[15];
    const float* e4_b = (const float*)d_in[16];
    const float* e5_w = (const float*)d_in[17];
    const float* e5_b = (const float*)d_in[18];
    const float* bn0_g = (const float*)d_in[19];
    const float* bn0_b = (const float*)d_in[20];
    const float* bn1_g = (const float*)d_in[21];
    const float* bn1_b = (const float*)d_in[22];
    float* out = (float*)d_out;

    // workspace layout
    float* ws = (float*)d_ws;
    float* bufA = ws;
    __hip_bfloat16* h2bf = (__hip_bfloat16*)bufA;                         // N*H bf16 (h2)
    __hip_bfloat16* h1bf = (__hip_bfloat16*)(bufA + (size_t)N_NODES * H); // N*H bf16
    int*   cntO = (int*)(h1bf + (size_t)N_NODES * H);                     // 50000
    unsigned* wc = (unsigned*)(cntO + N_NODES);                           // N*32 u32 (6.4MB)
    unsigned long long* statq = (unsigned long long*)(wc + (size_t)N_NODES * VOCAB); // 512 i64
    float* ii   = (float*)(statq + 512);
    int*   cntI = (int*)(ii + N_NODES);
    int*   row_ptr = cntI + N_NODES;                                      // 50001 -> pad 50048
    int*   col  = row_ptr + 50048;                                        // 600000
    unsigned char* binbase = (unsigned char*)(col + N_EDGES);             // N*32
    unsigned char* rank8   = binbase + (size_t)N_NODES * VOCAB;           // 600000
    float* t1   = (float*)(rank8 + ((N_EDGES + 63) & ~63));
    float* t2   = t1 + N_GRAPHS * H;
    int*   bsum  = (int*)(t2 + N_GRAPHS * H);                             // 256
    float* emb1  = (float*)(bsum + 256);                                  // 4096
    __hip_bfloat16* w2t = (__hip_bfloat16*)(emb1 + VOCAB * H);            // 16384 bf16

    // zero cntO + wc + statq
    k_zero<<<(ZERO_N16 + 255) / 256, 256, 0, stream>>>((uint4*)cntO, ZERO_N16);

    k_count_prep<<<EB + 160, 256, 0, stream>>>(edge_src, cntO, emb, W1, emb1, W2, w2t);
    k_hist32<<<EB, 256, 0, stream>>>(edge_src, edge_dst, node_feat, cntO, wc, rank8, N_EDGES);
    k_nodebins<<<SCAN_BLOCKS, 256, 0, stream>>>(wc, cntI, binbase, bsum, N_NODES);
    k_scatterscan<<<SCAN_BLOCKS, 256, 0, stream>>>(cntI, bsum, row_ptr, ii, N_NODES, SCAN_BLOCKS);
    k_fill_h1<<<EB + H1_BLOCKS, 256, 0, stream>>>(edge_src, edge_dst, node_feat, row_ptr,
                                                  binbase, rank8, col,
                                                  wc, emb1, ii, cntO, b1, h1bf);

    // layer 2: fused gather->LDS->MFMA
    k_gather_mfma<<<(N_NODES + GM_NODES - 1) / GM_NODES, 256, 0, stream>>>(
        h1bf, row_ptr, col, w2t, ii, b2, h2bf, N_NODES);

    // head: 3 kernels (stats accumulated by producers via fixpoint atomics)
    k_poolmlp1<<<N_GRAPHS, 128, 0, stream>>>(h2bf, graph_ids, e1_w, e1_b, t1, statq, N_NODES);
    k_mlp2bn<<<N_GRAPHS, 128, 0, stream>>>(t1, statq, statq + 256, bn0_g, bn0_b, e2_w, e2_b, t2);
    k_head<<<N_GRAPHS, 128, 0, stream>>>(t2, statq + 256, bn1_g, bn1_b,
                                         e3_w, e3_b, e4_w, e4_b, e5_w, e5_b, out);
}

// Round 20
// 189.567 us; speedup vs baseline: 3.4541x; 1.2373x over previous
//
#include <hip/hip_runtime.h>
#include <hip/hip_bf16.h>
#include <math.h>

#define N_NODES 50000
#define N_EDGES 600000
#define N_GRAPHS 1024
#define H 128
#define VOCAB 32
#define BN_EPS 1e-5f
#define SCAN_BLOCKS ((N_NODES + 255) / 256)   // 196
#define H1_NODES 64
#define H1_BLOCKS ((N_NODES + H1_NODES - 1) / H1_NODES)   // 782
#define EB ((N_EDGES + 255) / 256)            // 2344
#define GM_NODES 16
#define SROW 136
#define ZERO_BYTES ((size_t)N_NODES * 4 + (size_t)N_NODES * VOCAB * 4)
#define ZERO_N16 ((int)(ZERO_BYTES / 16))

typedef short bf8_t __attribute__((ext_vector_type(8)));
typedef float f4_t __attribute__((ext_vector_type(4)));

// ---------------- pass 0: zero cntO + wc32 ----------------
__global__ void k_zero(uint4* __restrict__ p, int n16) {
    int i = blockIdx.x * blockDim.x + threadIdx.x;
    if (i < n16) p[i] = uint4{0u, 0u, 0u, 0u};
}

// ---------------- pass 1: out-degree count + weight prep (fused) ----------------
__global__ void k_count_prep(const int* __restrict__ src, int* __restrict__ cntO,
                             const float* __restrict__ emb, const float* __restrict__ W1,
                             float* __restrict__ emb1,
                             const float* __restrict__ W2, __hip_bfloat16* __restrict__ w2t) {
    int b = blockIdx.x;
    int t = threadIdx.x;
    if (b < EB) {
        int i = b * 256 + t;
        if (i < N_EDGES) atomicAdd(&cntO[src[i]], 1);
    } else if (b < EB + 32) {
        if (t < 128) {
            int v = b - EB;
            float acc = 0.f;
            for (int k = 0; k < H; ++k) acc += emb[v * H + k] * W1[k * H + t];
            emb1[v * H + t] = acc;
        }
    } else {
        if (t < 128) {
            int k = b - EB - 32;
            w2t[(size_t)t * H + k] = __float2bfloat16(W2[(size_t)k * H + t]);
        }
    }
}

// ---------------- pass 2: fused weighted histogram + in-degree (u32 atomics) ----------
__global__ void k_hist32(const int* __restrict__ src, const int* __restrict__ dst,
                         const int* __restrict__ feat, const int* __restrict__ cntO,
                         unsigned* __restrict__ wc,
                         unsigned char* __restrict__ rank8, int E) {
    int i = blockIdx.x * blockDim.x + threadIdx.x;
    if (i >= E) return;
    int s = src[i], d = dst[i], v = feat[s];
    float o = rsqrtf(fmaxf((float)cntO[s], 1.f));
    unsigned q = __float2uint_rn(o * 1048576.0f);   // 2^20 fixpoint
    unsigned old = atomicAdd(&wc[(size_t)d * VOCAB + v], (1u << 27) | q);
    rank8[i] = (unsigned char)(old >> 27);
}

// ---------------- pass 3: per-node bin scan + cntI + per-256-node block sums ----------------
__global__ void k_nodebins(const unsigned* __restrict__ wc,
                           int* __restrict__ cntI, unsigned char* __restrict__ binbase,
                           int* __restrict__ bsum, int n) {
    __shared__ int scnt[256];
    int t = threadIdx.x;
    int wave = t >> 6, lane = t & 63;
    int sub = lane >> 5;
    int l32 = lane & 31;
    int nodeBase = blockIdx.x * 256;
#pragma unroll 4
    for (int it = 0; it < 32; ++it) {
        int local = wave * 64 + it * 2 + sub;
        int node = nodeBase + local;
        int c = 0;
        if (node < n && l32 < VOCAB)
            c = (int)(wc[(size_t)node * VOCAB + l32] >> 27);
        int inc = c;
#pragma unroll
        for (int off = 1; off < VOCAB; off <<= 1) {
            int u = __shfl_up(inc, off, 32);
            if (l32 >= off) inc += u;
        }
        if (node < n && l32 < VOCAB)
            binbase[(size_t)node * VOCAB + l32] = (unsigned char)(inc - c);
        if (l32 == VOCAB - 1) scnt[local] = (node < n) ? inc : 0;
    }
    __syncthreads();
    int node = nodeBase + t;
    if (node < n) cntI[node] = scnt[t];
    __shared__ int red[256];
    red[t] = scnt[t];
    __syncthreads();
    for (int off = 128; off > 0; off >>= 1) {
        if (t < off) red[t] += red[t + off];
        __syncthreads();
    }
    if (t == 0) bsum[blockIdx.x] = red[0];
}

// ---------------- pass 4: scatter-scan with inline (redundant) bsum scan ----------------
__global__ void k_scatterscan(const int* __restrict__ cntI, const int* __restrict__ bsum,
                              int* __restrict__ row_ptr, float* __restrict__ ii,
                              int n, int nb) {
    __shared__ int sb[256];
    __shared__ int sh[256];
    int t = threadIdx.x;
    int bv = (t < nb) ? bsum[t] : 0;
    sb[t] = bv;
    __syncthreads();
    for (int off = 1; off < 256; off <<= 1) {
        int u = (t >= off) ? sb[t - off] : 0;
        __syncthreads();
        sb[t] += u;
        __syncthreads();
    }
    int blockoff = (blockIdx.x == 0) ? 0 : sb[blockIdx.x - 1];
    int i = blockIdx.x * 256 + t;
    int v = (i < n) ? cntI[i] : 0;
    sh[t] = v;
    __syncthreads();
    for (int off = 1; off < 256; off <<= 1) {
        int u = (t >= off) ? sh[t - off] : 0;
        __syncthreads();
        sh[t] += u;
        __syncthreads();
    }
    if (i < n) {
        row_ptr[i] = blockoff + sh[t] - v;
        ii[i] = rsqrtf(fmaxf((float)v, 1.f));
    }
    if (blockIdx.x == 0 && t == 0) row_ptr[n] = sb[nb - 1];
}

// ---------------- pass 5 (fused): atomic-free CSR fill + layer-1 h1 compute ----------------
__global__ void k_fill_h1(const int* __restrict__ src, const int* __restrict__ dst,
                          const int* __restrict__ feat, const int* __restrict__ row_ptr,
                          const unsigned char* __restrict__ binbase,
                          const unsigned char* __restrict__ rank8,
                          int* __restrict__ col,
                          const unsigned* __restrict__ wc,
                          const float* __restrict__ emb1,
                          const float* __restrict__ ii, const int* __restrict__ cntO,
                          const float* __restrict__ b1, __hip_bfloat16* __restrict__ h1) {
    __shared__ float wl[H1_NODES * VOCAB];
    __shared__ float sii[H1_NODES], soi[H1_NODES];
    int tid = threadIdx.x;
    if (blockIdx.x < EB) {
        int i = blockIdx.x * 256 + tid;
        if (i < N_EDGES) {
            int s = src[i], d = dst[i], v = feat[s];
            int slot = row_ptr[d] + (int)binbase[(size_t)d * VOCAB + v] + (int)rank8[i];
            col[slot] = s;
        }
        return;
    }
    int hb = blockIdx.x - EB;
    int j = tid & 127;
    int g = tid >> 7;
    float ev[VOCAB];
#pragma unroll
    for (int v = 0; v < VOCAB; ++v) ev[v] = emb1[v * H + j];
    float bj = b1[j];

    int node0 = hb * H1_NODES;
    int nn = min(H1_NODES, N_NODES - node0);
    const unsigned* wsrc = wc + (size_t)node0 * VOCAB;
    for (int i = tid; i < nn * VOCAB; i += 256) {
        unsigned p = wsrc[i];
        wl[i] = (float)(p & 0x07FFFFFFu) * (1.0f / 1048576.0f);
    }
    for (int i = tid; i < nn; i += 256) {
        sii[i] = ii[node0 + i];
        soi[i] = rsqrtf(fmaxf((float)cntO[node0 + i], 1.f));
    }
    __syncthreads();

    int rbeg = g * 32;
    int rend = min(rbeg + 32, nn);
    for (int r = rbeg; r < rend; ++r) {
        const float4* wr = (const float4*)(wl + r * VOCAB);
        float acc = 0.f;
#pragma unroll
        for (int q = 0; q < VOCAB / 4; ++q) {
            float4 w4 = wr[q];
            acc += w4.x * ev[4 * q] + w4.y * ev[4 * q + 1]
                 + w4.z * ev[4 * q + 2] + w4.w * ev[4 * q + 3];
        }
        float val = fmaxf(acc * sii[r] + bj, 0.f);
        h1[(size_t)(node0 + r) * H + j] = __float2bfloat16(val * soi[r]);
    }
}

// ---------------- layer 2 (fused): gather into LDS -> MFMA, 16-node tile ----------------
__global__ __launch_bounds__(256) void k_gather_mfma(
        const __hip_bfloat16* __restrict__ h,
        const int* __restrict__ row_ptr, const int* __restrict__ col,
        const __hip_bfloat16* __restrict__ WT,
        const float* __restrict__ ii, const float* __restrict__ b,
        __hip_bfloat16* __restrict__ outp, int n) {
    __shared__ __hip_bfloat16 sA[GM_NODES * SROW];
    int tid = threadIdx.x;
    int wave = tid >> 6;
    int lane = tid & 63;
    int l16 = lane & 15;
    int sub = lane >> 4;
    int co = l16 * 8;
    int base = blockIdx.x * GM_NODES;

    int local = wave * 4 + sub;
    int node = base + local;
    float a0 = 0.f, a1 = 0.f, a2 = 0.f, a3 = 0.f;
    float a4 = 0.f, a5 = 0.f, a6 = 0.f, a7 = 0.f;
    if (node < n) {
        int beg = row_ptr[node];
        int end = row_ptr[node + 1];
        int e = beg;
        for (; e + 16 <= end; e += 16) {
            int s[16];
            uint4 v[16];
#pragma unroll
            for (int k = 0; k < 16; ++k) s[k] = col[e + k];
#pragma unroll
            for (int k = 0; k < 16; ++k)
                v[k] = *(const uint4*)(h + (size_t)s[k] * H + co);
#pragma unroll
            for (int k = 0; k < 16; ++k) {
                float2 f0 = __bfloat1622float2(*(__hip_bfloat162*)&v[k].x);
                float2 f1 = __bfloat1622float2(*(__hip_bfloat162*)&v[k].y);
                float2 f2 = __bfloat1622float2(*(__hip_bfloat162*)&v[k].z);
                float2 f3 = __bfloat1622float2(*(__hip_bfloat162*)&v[k].w);
                a0 += f0.x; a1 += f0.y; a2 += f1.x; a3 += f1.y;
                a4 += f2.x; a5 += f2.y; a6 += f3.x; a7 += f3.y;
            }
        }
        if (e < end) {
            int s[16];
            uint4 v[16];
#pragma unroll
            for (int k = 0; k < 16; ++k) s[k] = col[(e + k < end) ? e + k : e];
#pragma unroll
            for (int k = 0; k < 16; ++k)
                v[k] = *(const uint4*)(h + (size_t)s[k] * H + co);
#pragma unroll
            for (int k = 0; k < 16; ++k) {
                float mk = (e + k < end) ? 1.f : 0.f;
                float2 f0 = __bfloat1622float2(*(__hip_bfloat162*)&v[k].x);
                float2 f1 = __bfloat1622float2(*(__hip_bfloat162*)&v[k].y);
                float2 f2 = __bfloat1622float2(*(__hip_bfloat162*)&v[k].z);
                float2 f3 = __bfloat1622float2(*(__hip_bfloat162*)&v[k].w);
                a0 += mk * f0.x; a1 += mk * f0.y; a2 += mk * f1.x; a3 += mk * f1.y;
                a4 += mk * f2.x; a5 += mk * f2.y; a6 += mk * f3.x; a7 += mk * f3.y;
            }
        }
    }
    __hip_bfloat162 o0 = __float22bfloat162_rn(make_float2(a0, a1));
    __hip_bfloat162 o1 = __float22bfloat162_rn(make_float2(a2, a3));
    __hip_bfloat162 o2 = __float22bfloat162_rn(make_float2(a4, a5));
    __hip_bfloat162 o3 = __float22bfloat162_rn(make_float2(a6, a7));
    uint4 ov;
    ov.x = *(unsigned*)&o0; ov.y = *(unsigned*)&o1;
    ov.z = *(unsigned*)&o2; ov.w = *(unsigned*)&o3;
    *(uint4*)(&sA[local * SROW + co]) = ov;
    __syncthreads();

    int rl = l16;
    int kg = sub;
    f4_t acc[2];
    acc[0] = f4_t{0.f, 0.f, 0.f, 0.f};
    acc[1] = f4_t{0.f, 0.f, 0.f, 0.f};
    const __hip_bfloat16* arow = &sA[rl * SROW + kg * 8];
#pragma unroll
    for (int ks = 0; ks < 4; ++ks) {
        bf8_t a = *(const bf8_t*)(arow + ks * 32);
#pragma unroll
        for (int t = 0; t < 2; ++t) {
            int ct = wave * 2 + t;
            bf8_t bf = *(const bf8_t*)(WT + (size_t)(ct * 16 + rl) * H + ks * 32 + kg * 8);
            acc[t] = __builtin_amdgcn_mfma_f32_16x16x32_bf16(a, bf, acc[t], 0, 0, 0);
        }
    }
    int rbase = base + kg * 4;
#pragma unroll
    for (int r = 0; r < 4; ++r) {
        int nd = rbase + r;
        if (nd < n) {
            float s = ii[nd];
#pragma unroll
            for (int t = 0; t < 2; ++t) {
                int c = (wave * 2 + t) * 16 + rl;
                float v = acc[t][r] * s + b[c];
                outp[(size_t)nd * H + c] = __float2bfloat16(fmaxf(v, 0.f));
            }
        }
    }
}

// ---------------- pooling + first head GEMV; 8-deep register-staged pool loop --------
// 64 lanes x bf16x2 cover the 128-ch row; threads t and t+64... wait: 128 threads,
// thread t covers channels {2*(t&63), 2*(t&63)+1} for row-half (t>>6). Simpler:
// thread t loads __hip_bfloat162 at column 2*(t&63) of row subset (t>>6 parity).
__global__ void k_poolmlp1(const __hip_bfloat16* __restrict__ h, const int* __restrict__ gid,
                           const float* __restrict__ e1w, const float* __restrict__ e1b,
                           float* __restrict__ t1, int n) {
    __shared__ int bnd[2];
    __shared__ float row[128];
    int g = blockIdx.x, t = threadIdx.x;
    if (t == 0) {
        int lo = 0, hi = n;
        while (lo < hi) { int m = (lo + hi) >> 1; if (gid[m] < g) lo = m + 1; else hi = m; }
        bnd[0] = lo;
        int lo2 = lo, hi2 = n;
        while (lo2 < hi2) { int m = (lo2 + hi2) >> 1; if (gid[m] < g + 1) lo2 = m + 1; else hi2 = m; }
        bnd[1] = lo2;
    }
    __syncthreads();
    int beg = bnd[0], end = bnd[1];
    // pool: thread t sums channels {c0, c0+1} over rows beg+par, beg+par+2, ...
    // where c0 = 2*(t&63), par = t>>6. Two row-streams double parallelism; each
    // stream staged 8 deep -> up to 8 loads in flight per thread.
    int c0 = 2 * (t & 63);
    int par = t >> 6;
    float sx = 0.f, sy = 0.f;
    int i = beg + par;
    for (; i + 16 <= end; i += 16) {          // 8 rows per stream per batch
        __hip_bfloat162 v[8];
#pragma unroll
        for (int k = 0; k < 8; ++k)
            v[k] = *(const __hip_bfloat162*)(h + (size_t)(i + 2 * k) * H + c0);
#pragma unroll
        for (int k = 0; k < 8; ++k) {
            float2 f = __bfloat1622float2(v[k]);
            sx += f.x; sy += f.y;
        }
    }
    for (; i < end; i += 2) {
        float2 f = __bfloat1622float2(*(const __hip_bfloat162*)(h + (size_t)i * H + c0));
        sx += f.x; sy += f.y;
    }
    // combine the two parity streams via LDS
    __shared__ float px[128], py[128];
    px[t] = sx; py[t] = sy;
    __syncthreads();
    if (t < 64) {
        float inv = 1.f / fmaxf((float)(end - beg), 1.f);
        row[2 * t]     = (px[t] + px[t + 64]) * inv;
        row[2 * t + 1] = (py[t] + py[t + 64]) * inv;
    }
    __syncthreads();
    float acc = e1b[t];
    for (int k = 0; k < H; ++k) acc += row[k] * e1w[k * H + t];
    t1[g * H + t] = acc;
}

// ---------------- BN stats / head ----------------
__global__ void k_bnstat(const float* __restrict__ x, float* __restrict__ stats, int G) {
    int c = blockIdx.x;
    float s = 0.f, s2 = 0.f;
    for (int g = threadIdx.x; g < G; g += blockDim.x) {
        float v = x[g * H + c];
        s += v; s2 += v * v;
    }
    __shared__ float rs[256], rs2[256];
    rs[threadIdx.x] = s; rs2[threadIdx.x] = s2;
    __syncthreads();
    for (int off = 128; off > 0; off >>= 1) {
        if (threadIdx.x < off) { rs[threadIdx.x] += rs[threadIdx.x + off]; rs2[threadIdx.x] += rs2[threadIdx.x + off]; }
        __syncthreads();
    }
    if (threadIdx.x == 0) {
        float mu = rs[0] / G;
        stats[c] = mu;
        stats[H + c] = rs2[0] / G - mu * mu;
    }
}

__global__ void k_mlp2bn(const float* __restrict__ t1, const float* __restrict__ stats,
                         const float* __restrict__ gam, const float* __restrict__ bet,
                         const float* __restrict__ W, const float* __restrict__ bias,
                         float* __restrict__ t2) {
    __shared__ float x[128];
    int g = blockIdx.x, t = threadIdx.x;
    float v = t1[g * H + t];
    v = (v - stats[t]) * rsqrtf(stats[H + t] + BN_EPS) * gam[t] + bet[t];
    x[t] = (v >= 0.f) ? v : 0.05f * v;
    __syncthreads();
    float acc = bias[t];
    for (int k = 0; k < H; ++k) acc += x[k] * W[k * H + t];
    t2[g * H + t] = acc;
}

__global__ void k_head(const float* __restrict__ t2, const float* __restrict__ stats,
                       const float* __restrict__ gam, const float* __restrict__ bet,
                       const float* __restrict__ e3w, const float* __restrict__ e3b,
                       const float* __restrict__ e4w, const float* __restrict__ e4b,
                       const float* __restrict__ e5w, const float* __restrict__ e5b,
                       float* __restrict__ out) {
    __shared__ float x[128], h3[64], h4[32];
    int g = blockIdx.x, t = threadIdx.x;
    float v = t2[g * H + t];
    v = (v - stats[t]) * rsqrtf(stats[H + t] + BN_EPS) * gam[t] + bet[t];
    x[t] = (v >= 0.f) ? v : 0.05f * v;
    __syncthreads();
    if (t < 64) {
        float a = e3b[t];
        for (int k = 0; k < 128; ++k) a += x[k] * e3w[k * 64 + t];
        h3[t] = (a >= 0.f) ? a : 0.1f * a;
    }
    __syncthreads();
    if (t < 32) {
        float a = e4b[t];
        for (int k = 0; k < 64; ++k) a += h3[k] * e4w[k * 32 + t];
        h4[t] = (a >= 0.f) ? a : 0.1f * a;
    }
    __syncthreads();
    if (t == 0) {
        float y0 = e5b[0], y1 = e5b[1];
        for (int k = 0; k < 32; ++k) {
            y0 += h4[k] * e5w[2 * k];
            y1 += h4[k] * e5w[2 * k + 1];
        }
        float m = fmaxf(y0, y1);
        float l = m + logf(expf(y0 - m) + expf(y1 - m));
        out[2 * g] = y0 - l;
        out[2 * g + 1] = y1 - l;
    }
}

extern "C" void kernel_launch(void* const* d_in, const int* in_sizes, int n_in,
                              void* d_out, int out_size, void* d_ws, size_t ws_size,
                              hipStream_t stream) {
    const int*   node_feat = (const int*)d_in[0];
    const int*   edge_src  = (const int*)d_in[1];
    const int*   edge_dst  = (const int*)d_in[2];
    const int*   graph_ids = (const int*)d_in[3];
    const float* emb  = (const float*)d_in[4];
    const float* W1   = (const float*)d_in[5];
    const float* b1   = (const float*)d_in[6];
    const float* W2   = (const float*)d_in[7];
    const float* b2   = (const float*)d_in[8];
    const float* e1_w = (const float*)d_in[9];
    const float* e1_b = (const float*)d_in[10];
    const float* e2_w = (const float*)d_in[11];
    const float* e2_b = (const float*)d_in[12];
    const float* e3_w = (const float*)d_in[13];
    const float* e3_b = (const float*)d_in[14];
    const float* e4_w = (const float*)d_in[15];
    const float* e4_b = (const float*)d_in[16];
    const float* e5_w = (const float*)d_in[17];
    const float* e5_b = (const float*)d_in[18];
    const float* bn0_g = (const float*)d_in[19];
    const float* bn0_b = (const float*)d_in[20];
    const float* bn1_g = (const float*)d_in[21];
    const float* bn1_b = (const float*)d_in[22];
    float* out = (float*)d_out;

    // workspace layout
    float* ws = (float*)d_ws;
    float* bufA = ws;
    __hip_bfloat16* h2bf = (__hip_bfloat16*)bufA;                         // N*H bf16 (h2)
    __hip_bfloat16* h1bf = (__hip_bfloat16*)(bufA + (size_t)N_NODES * H); // N*H bf16
    int*   cntO = (int*)(h1bf + (size_t)N_NODES * H);                     // 50000
    unsigned* wc = (unsigned*)(cntO + N_NODES);                           // N*32 u32 (6.4MB)
    float* ii   = (float*)(wc + (size_t)N_NODES * VOCAB);
    int*   cntI = (int*)(ii + N_NODES);
    int*   row_ptr = cntI + N_NODES;                                      // 50001 -> pad 50048
    int*   col  = row_ptr + 50048;                                        // 600000
    unsigned char* binbase = (unsigned char*)(col + N_EDGES);             // N*32
    unsigned char* rank8   = binbase + (size_t)N_NODES * VOCAB;           // 600000
    float* t1   = (float*)(rank8 + ((N_EDGES + 63) & ~63));
    float* t2   = t1 + N_GRAPHS * H;
    float* stats = t2 + N_GRAPHS * H;                                     // 512
    int*   bsum  = (int*)(stats + 4 * H);                                 // 256
    float* emb1  = (float*)(bsum + 256);                                  // 4096
    __hip_bfloat16* w2t = (__hip_bfloat16*)(emb1 + VOCAB * H);            // 16384 bf16

    // zero cntO + wc
    k_zero<<<(ZERO_N16 + 255) / 256, 256, 0, stream>>>((uint4*)cntO, ZERO_N16);

    k_count_prep<<<EB + 160, 256, 0, stream>>>(edge_src, cntO, emb, W1, emb1, W2, w2t);
    k_hist32<<<EB, 256, 0, stream>>>(edge_src, edge_dst, node_feat, cntO, wc, rank8, N_EDGES);
    k_nodebins<<<SCAN_BLOCKS, 256, 0, stream>>>(wc, cntI, binbase, bsum, N_NODES);
    k_scatterscan<<<SCAN_BLOCKS, 256, 0, stream>>>(cntI, bsum, row_ptr, ii, N_NODES, SCAN_BLOCKS);
    k_fill_h1<<<EB + H1_BLOCKS, 256, 0, stream>>>(edge_src, edge_dst, node_feat, row_ptr,
                                                  binbase, rank8, col,
                                                  wc, emb1, ii, cntO, b1, h1bf);

    // layer 2: fused gather->LDS->MFMA
    k_gather_mfma<<<(N_NODES + GM_NODES - 1) / GM_NODES, 256, 0, stream>>>(
        h1bf, row_ptr, col, w2t, ii, b2, h2bf, N_NODES);

    // pooling + head (r16 structure, pool loop register-staged)
    k_poolmlp1<<<N_GRAPHS, 128, 0, stream>>>(h2bf, graph_ids, e1_w, e1_b, t1, N_NODES);
    k_bnstat<<<H, 256, 0, stream>>>(t1, stats, N_GRAPHS);
    k_mlp2bn<<<N_GRAPHS, 128, 0, stream>>>(t1, stats, bn0_g, bn0_b, e2_w, e2_b, t2);
    k_bnstat<<<H, 256, 0, stream>>>(t2, stats + 2 * H, N_GRAPHS);
    k_head<<<N_GRAPHS, 128, 0, stream>>>(t2, stats + 2 * H, bn1_g, bn1_b,
                                         e3_w, e3_b, e4_w, e4_b, e5_w, e5_b, out);
}